// Round 12
// baseline (915.334 us; speedup 1.0000x reference)
//
#include <hip/hip_runtime.h>
#include <hip/hip_cooperative_groups.h>

namespace cg = cooperative_groups;

#define D 256
typedef __attribute__((ext_vector_type(8))) short short8;
typedef __attribute__((ext_vector_type(4))) float floatx4;

__device__ __forceinline__ unsigned short f2bf(float f) {
  unsigned int u = __float_as_uint(f);
  u = (u + 0x7FFF + ((u >> 16) & 1)) >> 16;   // RNE
  return (unsigned short)u;
}
__device__ __forceinline__ float bf2f(unsigned short h) {
  return __uint_as_float(((unsigned int)h) << 16);
}

// ---------------- cooperative fused setup + CSR build ----------------
// Phases (grid.sync between): P0 zero|bounds|cvt|cvt_w, P1 count,
// P2 block sums, P3 scan block sums, P4 per-slice scan, P5 place.
// Replaces 6 serialized launches (round 11: ~110 us incl. gaps).
__global__ __launch_bounds__(256) void k_csr(
    int* __restrict__ cur, int RN,
    const int* __restrict__ batch, int* __restrict__ gstart, int N, int G,
    const float* __restrict__ table, unsigned short* __restrict__ tableb, int TN,
    const float* __restrict__ root1, const float* __restrict__ W1,
    const float* __restrict__ root2, const float* __restrict__ W2,
    unsigned short* __restrict__ wb,
    const int* __restrict__ src, const int* __restrict__ dst,
    const int* __restrict__ et, const int* __restrict__ x, int E,
    int* __restrict__ esx, int* __restrict__ ess,
    int* __restrict__ off, int* __restrict__ bsum, int nb) {
  cg::grid_group grid = cg::this_grid();
  const int tid = threadIdx.x, bid = blockIdx.x;
  const int gtid = bid * 256 + tid, gsz = gridDim.x * 256;
  __shared__ int s[256];

  // ---- P0: independent prep ----
  for (int i = gtid; i < RN; i += gsz) cur[i] = 0;
  for (int i = gtid; i < N; i += gsz) {
    int bb = batch[i];
    if (i == 0) { for (int g = 0; g <= bb; g++) gstart[g] = 0; }
    else { int pb = batch[i - 1]; for (int g = pb + 1; g <= bb; g++) gstart[g] = i; }
    if (i == N - 1) { for (int g = bb + 1; g <= G; g++) gstart[g] = N; }
  }
  for (int i = gtid; i < TN; i += gsz) tableb[i] = f2bf(table[i]);
  for (int i = gtid; i < 2 * 4 * 65536; i += gsz) {
    int layer = i >> 18;            // 4*65536 = 2^18
    int idx = i & 262143;
    int mat = idx >> 16, rem = idx & 65535;
    int n = rem >> 8, k = rem & 255;
    const float* root = layer ? root2 : root1;
    const float* W = layer ? W2 : W1;
    const float* sp = (mat == 0) ? root : (W + (size_t)(mat - 1) * 65536);
    wb[i] = f2bf(sp[k * 256 + n]);
  }
  __threadfence();
  grid.sync();

  // ---- P1: per-(rel,dst) counts ----
  for (int e = gtid; e < E; e += gsz)
    atomicAdd(&cur[et[e] * N + dst[e]], 1);
  __threadfence();
  grid.sync();

  // ---- P2: per-block partial sums over 1024-slices ----
  if (bid < nb) {
    int base = bid * 1024;
    int a = 0;
#pragma unroll
    for (int j = 0; j < 4; j++) {
      int i = base + tid * 4 + j;
      if (i < RN) a += cur[i];
    }
    s[tid] = a; __syncthreads();
    for (int o = 128; o > 0; o >>= 1) {
      if (tid < o) s[tid] += s[tid + o];
      __syncthreads();
    }
    if (tid == 0) bsum[bid] = s[0];
  }
  __threadfence();
  grid.sync();

  // ---- P3: block 0 exclusive-scans bsum (nb <= 1024) ----
  if (bid == 0) {
    int v[4]; int a = 0;
#pragma unroll
    for (int j = 0; j < 4; j++) {
      int i = tid * 4 + j;
      v[j] = (i < nb) ? bsum[i] : 0;
      a += v[j];
    }
    s[tid] = a; __syncthreads();
    for (int o = 1; o < 256; o <<= 1) {
      int x_ = (tid >= o) ? s[tid - o] : 0;
      __syncthreads();
      s[tid] += x_;
      __syncthreads();
    }
    int excl = (tid > 0) ? s[tid - 1] : 0;
#pragma unroll
    for (int j = 0; j < 4; j++) {
      int i = tid * 4 + j;
      if (i < nb) { bsum[i] = excl; excl += v[j]; }
    }
    if (tid == 255) off[RN] = s[255];
  }
  __threadfence();
  grid.sync();

  // ---- P4: per-slice exclusive scan -> off, cur ----
  if (bid < nb) {
    int base = bid * 1024;
    int v[4]; int a = 0;
#pragma unroll
    for (int j = 0; j < 4; j++) {
      int i = base + tid * 4 + j;
      v[j] = (i < RN) ? cur[i] : 0;
      a += v[j];
    }
    s[tid] = a; __syncthreads();
    for (int o = 1; o < 256; o <<= 1) {
      int x_ = (tid >= o) ? s[tid - o] : 0;
      __syncthreads();
      s[tid] += x_;
      __syncthreads();
    }
    int excl = (tid > 0 ? s[tid - 1] : 0) + bsum[bid];
#pragma unroll
    for (int j = 0; j < 4; j++) {
      int i = base + tid * 4 + j;
      if (i < RN) { off[i] = excl; cur[i] = excl; excl += v[j]; }
    }
  }
  __threadfence();
  grid.sync();

  // ---- P5: CSR placement ----
  for (int e = gtid; e < E; e += gsz) {
    int sv = src[e];
    int pos = atomicAdd(&cur[et[e] * N + dst[e]], 1);
    esx[pos] = x[sv];
    ess[pos] = sv;
  }
}

// ---------------- relation aggregation, 8 ids per wave (ILP batch) --------
__global__ __launch_bounds__(256) void k_agg(const unsigned short* __restrict__ h,
    const int* __restrict__ rows, const int* __restrict__ off,
    unsigned short* __restrict__ out, int RN) {
  const int wave = threadIdx.x >> 6, lane = threadIdx.x & 63;
  const int base = (blockIdx.x * 4 + wave) * 8;
  if (base >= RN) return;

  int lo[8], hi[8];
#pragma unroll
  for (int j = 0; j < 8; j++) {
    int id = base + j;
    lo[j] = (id < RN) ? off[id] : 0;
    hi[j] = (id < RN) ? off[id + 1] : 0;
  }

  int r0[8];
#pragma unroll
  for (int j = 0; j < 8; j++)
    r0[j] = (hi[j] > lo[j]) ? rows[lo[j]] : 0;

  ushort4 v0[8];
#pragma unroll
  for (int j = 0; j < 8; j++)
    v0[j] = (hi[j] > lo[j])
        ? *(const ushort4*)(h + (size_t)r0[j] * D + lane * 4)
        : make_ushort4(0, 0, 0, 0);

  float a[8][4];
#pragma unroll
  for (int j = 0; j < 8; j++) {
    a[j][0] = bf2f(v0[j].x); a[j][1] = bf2f(v0[j].y);
    a[j][2] = bf2f(v0[j].z); a[j][3] = bf2f(v0[j].w);
  }

#pragma unroll
  for (int j = 0; j < 8; j++) {
    for (int p = lo[j] + 1; p < hi[j]; ++p) {
      int r = rows[p];
      ushort4 v = *(const ushort4*)(h + (size_t)r * D + lane * 4);
      a[j][0] += bf2f(v.x); a[j][1] += bf2f(v.y);
      a[j][2] += bf2f(v.z); a[j][3] += bf2f(v.w);
    }
  }

#pragma unroll
  for (int j = 0; j < 8; j++) {
    int id = base + j;
    if (id >= RN) continue;
    int c = hi[j] - lo[j];
    float inv = 1.0f / (float)(c > 0 ? c : 1);
    ushort4 o;
    o.x = f2bf(a[j][0] * inv); o.y = f2bf(a[j][1] * inv);
    o.z = f2bf(a[j][2] * inv); o.w = f2bf(a[j][3] * inv);
    *(ushort4*)(out + (size_t)id * D + lane * 4) = o;
  }
}

// ---------------- fused K=1024 bf16 MFMA GEMM, 128x256 block, 8 waves ------
// ROUND-8 PROVEN SHAPE (96.6 us): BK=32, 30 KB LDS, VGPR 56. Do NOT raise BK
// (round 9: BK=64 -> 76 KB LDS + reg spill -> 150 MB scratch writes, 2.5x slower).
// SQ_LDS_BANK_CONFLICT ~1.1e7 here is intrinsic b128 multi-phase service, not
// fixable aliasing (2-way max with the 40-ushort pad = free).
__global__ __launch_bounds__(512) void k_lgemm(
    const unsigned short* __restrict__ Aroot, const int* __restrict__ gidx,
    const unsigned short* agg, const unsigned short* __restrict__ wb,
    const float* __restrict__ bias, unsigned short* Cout, int M, int N) {
  __shared__ unsigned short AsU[128 * 40];       // 10 KB [row][k] pad->40
  __shared__ unsigned short BsU[256 * 40];       // 20 KB [n][k]   pad->40
  const int tid = threadIdx.x;
  const int w = tid >> 6, lane = tid & 63;
  const int wr = w >> 2, wc = w & 3;             // wave grid 2x4
  const int i0 = blockIdx.x * 128;
  const int ml = lane & 15, q = lane >> 4;

  const int srow = tid >> 2;       // 0..127
  const int schunk = tid & 3;      // 16B chunk within 64B k-slice
  int r0 = i0 + srow;
  int r0c = (r0 < M) ? r0 : (M - 1);
  const int rowA0 = gidx ? gidx[r0c] : r0c;

  const unsigned short* a0base[4];
  a0base[0] = Aroot + (size_t)rowA0 * D + schunk * 8;
#pragma unroll
  for (int r = 0; r < 3; r++)
    a0base[r + 1] = agg + ((size_t)r * N + r0c) * D + schunk * 8;

  floatx4 acc[4][4];
#pragma unroll
  for (int i = 0; i < 4; i++)
#pragma unroll
    for (int j = 0; j < 4; j++) acc[i][j] = (floatx4){0.f, 0.f, 0.f, 0.f};

  // prefetch registers (step 0)
  uint4 av0, bv0, bv1;
  {
    av0 = *(const uint4*)(a0base[0]);
    const unsigned short* bb = wb + (size_t)srow * D + schunk * 8;
    bv0 = *(const uint4*)(bb);
    bv1 = *(const uint4*)(bb + 128 * D);
  }

  for (int step = 0; step < 32; ++step) {
    __syncthreads();   // previous step's LDS consumers done
    *(uint4*)&AsU[srow * 40 + schunk * 8] = av0;
    *(uint4*)&BsU[srow * 40 + schunk * 8] = bv0;
    *(uint4*)&BsU[(srow + 128) * 40 + schunk * 8] = bv1;
    __syncthreads();

    // issue next step's loads now — they fly under the compute below
    {
      int ns = (step < 31) ? step + 1 : 31;
      int seg = ns >> 3, kloc = (ns & 7) * 32;
      av0 = *(const uint4*)(a0base[seg] + kloc);
      const unsigned short* bb =
          wb + (size_t)seg * 65536 + (size_t)srow * D + schunk * 8 + kloc;
      bv0 = *(const uint4*)(bb);
      bv1 = *(const uint4*)(bb + 128 * D);
    }

    short8 aF[4], bF[4];
#pragma unroll
    for (int mi = 0; mi < 4; mi++)
      aF[mi] = *(const short8*)&AsU[(wr * 64 + mi * 16 + ml) * 40 + q * 8];
#pragma unroll
    for (int ni = 0; ni < 4; ni++)
      bF[ni] = *(const short8*)&BsU[(wc * 64 + ni * 16 + ml) * 40 + q * 8];
#pragma unroll
    for (int mi = 0; mi < 4; mi++)
#pragma unroll
      for (int ni = 0; ni < 4; ni++)
        acc[mi][ni] = __builtin_amdgcn_mfma_f32_16x16x32_bf16(
            aF[mi], bF[ni], acc[mi][ni], 0, 0, 0);
  }

  // epilogue: bias + ReLU + bf16; C/D layout col=lane&15, row=q*4+reg
  float bv[4];
#pragma unroll
  for (int ni = 0; ni < 4; ni++) bv[ni] = bias[wc * 64 + ni * 16 + ml];
#pragma unroll
  for (int mi = 0; mi < 4; mi++) {
#pragma unroll
    for (int ni = 0; ni < 4; ni++) {
      int col = wc * 64 + ni * 16 + ml;
#pragma unroll
      for (int j = 0; j < 4; j++) {
        int row = i0 + wr * 64 + mi * 16 + q * 4 + j;
        if (row < M) {
          float v = fmaxf(acc[mi][ni][j] + bv[ni], 0.f);
          Cout[(size_t)row * D + col] = f2bf(v);
        }
      }
    }
  }
}

// ---------------- fused graph mean-pool + linear head ----------------
__global__ __launch_bounds__(256) void k_poolfinal(
    const unsigned short* __restrict__ h, const int* __restrict__ gstart,
    const float* __restrict__ linW, const float* __restrict__ linb,
    float* __restrict__ out, int G) {
  __shared__ float red[4][D];
  __shared__ float sred[4][4];
  int g = blockIdx.x;
  int lo = gstart[g], hi = gstart[g + 1];
  int tid = threadIdx.x, wave = tid >> 6, lane = tid & 63;
  float a0 = 0.f, a1 = 0.f, a2 = 0.f, a3 = 0.f;
  for (int i = lo + wave; i < hi; i += 4) {
    ushort4 v = *(const ushort4*)(h + (size_t)i * D + lane * 4);
    a0 += bf2f(v.x); a1 += bf2f(v.y); a2 += bf2f(v.z); a3 += bf2f(v.w);
  }
  red[wave][lane * 4 + 0] = a0;
  red[wave][lane * 4 + 1] = a1;
  red[wave][lane * 4 + 2] = a2;
  red[wave][lane * 4 + 3] = a3;
  __syncthreads();
  float s = red[0][tid] + red[1][tid] + red[2][tid] + red[3][tid];
  float inv = (hi > lo) ? 1.0f / (float)(hi - lo) : 0.0f;
  float m = s * inv;                       // mean feature tid
  float4 wrow = *(const float4*)(linW + tid * 4);
  float p0 = m * wrow.x, p1 = m * wrow.y, p2 = m * wrow.z, p3 = m * wrow.w;
  for (int o = 32; o > 0; o >>= 1) {
    p0 += __shfl_down(p0, o, 64);
    p1 += __shfl_down(p1, o, 64);
    p2 += __shfl_down(p2, o, 64);
    p3 += __shfl_down(p3, o, 64);
  }
  if (lane == 0) {
    sred[wave][0] = p0; sred[wave][1] = p1;
    sred[wave][2] = p2; sred[wave][3] = p3;
  }
  __syncthreads();
  if (tid < 4)
    out[g * 4 + tid] = sred[0][tid] + sred[1][tid] + sred[2][tid] +
                       sred[3][tid] + linb[tid];
}

extern "C" void kernel_launch(void* const* d_in, const int* in_sizes, int n_in,
                              void* d_out, int out_size, void* d_ws, size_t ws_size,
                              hipStream_t stream) {
  const int*   x     = (const int*)d_in[0];
  const int*   ei    = (const int*)d_in[1];
  const int*   et    = (const int*)d_in[2];
  const int*   batch = (const int*)d_in[3];
  const float* table = (const float*)d_in[5];
  const float* W1    = (const float*)d_in[6];
  const float* root1 = (const float*)d_in[7];
  const float* b1    = (const float*)d_in[8];
  const float* W2    = (const float*)d_in[9];
  const float* root2 = (const float*)d_in[10];
  const float* b2    = (const float*)d_in[11];
  const float* linW  = (const float*)d_in[12];
  const float* linb  = (const float*)d_in[13];
  float* out = (float*)d_out;

  const int N = in_sizes[0];
  const int E = in_sizes[2];
  const int G = out_size / 4;
  const int TN = in_sizes[5];           // VOC * D
  const int* src = ei;
  const int* dst = ei + E;
  const int RN = 3 * N;

  // ---- ws layout (~210 MB), page aliasing proven rounds 5-11 ----
  char* wsb = (char*)d_ws;
  size_t pg = (size_t)N * D * 2;
  unsigned short* P0 = (unsigned short*)wsb;
  unsigned short* P1 = (unsigned short*)(wsb + pg);
  unsigned short* P3 = (unsigned short*)(wsb + 3 * pg);
  unsigned short* wb = (unsigned short*)(wsb + 4 * pg);  // 2 layers x 4 mats
  int*   off    = (int*)(wb + 2 * 4 * 65536);
  int*   esx    = off + (RN + 1);       // L1 row ids (= x[src])
  int*   ess    = esx + E;              // L2 row ids (= src)
  int*   gstart = ess + E;
  unsigned short* tableb = P3;          // alias (dead before L2 agg writes P3)
  int* cur  = (int*)P0;                 // alias (dead before L1 agg writes P0)
  int* bsum = cur + RN;                 // alias

  int nb = (RN + 1023) / 1024;          // 293 <= 512 blocks (co-resident)

  // ---- one cooperative launch for all setup + CSR ----
  {
    int rn = RN, n_ = N, g_ = G, tn = TN, e_ = E, nb_ = nb;
    void* args[] = {
      (void*)&cur, (void*)&rn,
      (void*)&batch, (void*)&gstart, (void*)&n_, (void*)&g_,
      (void*)&table, (void*)&tableb, (void*)&tn,
      (void*)&root1, (void*)&W1, (void*)&root2, (void*)&W2,
      (void*)&wb,
      (void*)&src, (void*)&dst, (void*)&et, (void*)&x, (void*)&e_,
      (void*)&esx, (void*)&ess, (void*)&off, (void*)&bsum, (void*)&nb_,
    };
    hipLaunchCooperativeKernel((void*)k_csr, dim3(512), dim3(256),
                               args, 0, stream);
  }

  const int gagg = (RN + 31) / 32;      // 8 ids/wave x 4 waves
  const int ggemm = (N + 127) / 128;

  // ---- layer 1 ----
  k_agg<<<gagg, 256, 0, stream>>>(tableb, esx, off, P0, RN);
  k_lgemm<<<ggemm, 512, 0, stream>>>(tableb, x, P0, wb, b1, P0, N, N);
  // ---- layer 2 ----
  k_agg<<<gagg, 256, 0, stream>>>(P0, ess, off, P1, RN);
  k_lgemm<<<ggemm, 512, 0, stream>>>(P0, nullptr, P1, wb + 4 * 65536, b2, P1, N, N);

  // ---- pool + head fused ----
  k_poolfinal<<<G, 256, 0, stream>>>(P1, gstart, linW, linb, out, G);
}

// Round 13
// 454.292 us; speedup vs baseline: 2.0149x; 2.0149x over previous
//
#include <hip/hip_runtime.h>

#define D 256
typedef __attribute__((ext_vector_type(8))) short short8;
typedef __attribute__((ext_vector_type(4))) float floatx4;

__device__ __forceinline__ unsigned short f2bf(float f) {
  unsigned int u = __float_as_uint(f);
  u = (u + 0x7FFF + ((u >> 16) & 1)) >> 16;   // RNE
  return (unsigned short)u;
}
__device__ __forceinline__ float bf2f(unsigned short h) {
  return __uint_as_float(((unsigned int)h) << 16);
}

// ---------------- fused independent setup: zero | bounds | cvt | cvt_w x2 --
// also zeroes the lookback flags for k_scanlb.
__global__ __launch_bounds__(256) void k_setup(
    int* __restrict__ cur, int RN, int* __restrict__ flags, int nb,
    const int* __restrict__ batch, int* __restrict__ gstart, int N, int G,
    const float* __restrict__ table, unsigned short* __restrict__ tableb, int TN,
    const float* __restrict__ root1, const float* __restrict__ W1,
    const float* __restrict__ root2, const float* __restrict__ W2,
    unsigned short* __restrict__ wb,
    int g0, int g1, int g2, int g3) {
  int b = blockIdx.x, t = threadIdx.x;
  if (b < g0) {                       // zero cur + flags
    int i = b * 1024 + t * 4;
#pragma unroll
    for (int j = 0; j < 4; j++) if (i + j < RN) cur[i + j] = 0;
    if (b == 0 && t < nb) flags[t] = 0;          // nb=293 > 256: handle rest
    if (b == 1 && 256 + t < nb) flags[256 + t] = 0;
  } else if (b < g1) {                // graph bounds
    int i = (b - g0) * 256 + t;
    if (i >= N) return;
    int bb = batch[i];
    if (i == 0) { for (int g = 0; g <= bb; g++) gstart[g] = 0; }
    else { int pb = batch[i - 1]; for (int g = pb + 1; g <= bb; g++) gstart[g] = i; }
    if (i == N - 1) { for (int g = bb + 1; g <= G; g++) gstart[g] = N; }
  } else if (b < g2) {                // table fp32 -> bf16
    int i = (b - g1) * 256 + t;
    if (i < TN) tableb[i] = f2bf(table[i]);
  } else {                            // weights -> bf16 transposed [mat][n][k]
    int layer = (b < g3) ? 0 : 1;
    int idx = ((b - (layer ? g3 : g2)) * 256 + t);   // 0 .. 4*65536-1
    int mat = idx >> 16, rem = idx & 65535;
    int n = rem >> 8, k = rem & 255;
    const float* root = layer ? root2 : root1;
    const float* W = layer ? W2 : W1;
    const float* s = (mat == 0) ? root : (W + (size_t)(mat - 1) * 65536);
    wb[(size_t)layer * 4 * 65536 + idx] = f2bf(s[k * 256 + n]);
  }
}

// ---------------- per-(relation,node) in-edge counts ----------------
__global__ __launch_bounds__(256) void k_count_i(const int* __restrict__ dst,
    const int* __restrict__ et, int* __restrict__ cnt, int E, int N) {
  int e = blockIdx.x * 256 + threadIdx.x;
  if (e >= E) return;
  atomicAdd(&cnt[et[e] * N + dst[e]], 1);
}

// ---------------- single-pass exclusive scan (decoupled lookback) ----------
// in -> off (exclusive scan) and cur (copy of off). Block b handles a
// 1024-slice. agg[b]/inc[b] + flags[b] (0=none, 1=agg ready, 2=inclusive
// ready). 293 blocks, all co-resident -> spin is deadlock-free.
__global__ __launch_bounds__(256) void k_scanlb(const int* __restrict__ in,
    int* __restrict__ off, int* __restrict__ cur,
    volatile int* __restrict__ flags, volatile int* __restrict__ aggv,
    volatile int* __restrict__ incv, int n, int nb) {
  __shared__ int s[256];
  __shared__ int sexcl;
  const int b = blockIdx.x, t = threadIdx.x;
  const int base = b * 1024;

  int v[4]; int a = 0;
#pragma unroll
  for (int j = 0; j < 4; j++) {
    int i = base + t * 4 + j;
    v[j] = (i < n) ? in[i] : 0;
    a += v[j];
  }
  s[t] = a; __syncthreads();
  for (int o = 1; o < 256; o <<= 1) {
    int x_ = (t >= o) ? s[t - o] : 0;
    __syncthreads();
    s[t] += x_;
    __syncthreads();
  }
  const int aggregate = s[255];

  if (t == 0) {
    if (b == 0) {
      incv[0] = aggregate;
      __threadfence();
      flags[0] = 2;
      sexcl = 0;
    } else {
      aggv[b] = aggregate;
      __threadfence();
      flags[b] = 1;
      // lookback
      int excl = 0;
      for (int i = b - 1; i >= 0; ) {
        int f = flags[i];
        if (f == 0) continue;            // spin
        if (f == 2) { excl += incv[i]; break; }
        excl += aggv[i]; --i;
      }
      incv[b] = excl + aggregate;
      __threadfence();
      flags[b] = 2;
      sexcl = excl;
    }
  }
  __syncthreads();

  int excl = (t > 0 ? s[t - 1] : 0) + sexcl;
#pragma unroll
  for (int j = 0; j < 4; j++) {
    int i = base + t * 4 + j;
    if (i < n) { off[i] = excl; cur[i] = excl; excl += v[j]; }
  }
  if (b == nb - 1 && t == 255) off[n] = excl;   // total = E
}

// CSR placement: esx[pos] = x[src] (L1 row id), ess[pos] = src (L2 row id)
__global__ __launch_bounds__(256) void k_place2(const int* __restrict__ src,
    const int* __restrict__ dst, const int* __restrict__ et,
    const int* __restrict__ x, int* __restrict__ cur,
    int* __restrict__ esx, int* __restrict__ ess, int E, int N) {
  int e = blockIdx.x * 256 + threadIdx.x;
  if (e >= E) return;
  int s = src[e];
  int pos = atomicAdd(&cur[et[e] * N + dst[e]], 1);
  esx[pos] = x[s];
  ess[pos] = s;
}

// ---------------- relation aggregation, 8 ids per wave (ILP batch) --------
__global__ __launch_bounds__(256) void k_agg(const unsigned short* __restrict__ h,
    const int* __restrict__ rows, const int* __restrict__ off,
    unsigned short* __restrict__ out, int RN) {
  const int wave = threadIdx.x >> 6, lane = threadIdx.x & 63;
  const int base = (blockIdx.x * 4 + wave) * 8;
  if (base >= RN) return;

  int lo[8], hi[8];
#pragma unroll
  for (int j = 0; j < 8; j++) {
    int id = base + j;
    lo[j] = (id < RN) ? off[id] : 0;
    hi[j] = (id < RN) ? off[id + 1] : 0;
  }

  int r0[8];
#pragma unroll
  for (int j = 0; j < 8; j++)
    r0[j] = (hi[j] > lo[j]) ? rows[lo[j]] : 0;

  ushort4 v0[8];
#pragma unroll
  for (int j = 0; j < 8; j++)
    v0[j] = (hi[j] > lo[j])
        ? *(const ushort4*)(h + (size_t)r0[j] * D + lane * 4)
        : make_ushort4(0, 0, 0, 0);

  float a[8][4];
#pragma unroll
  for (int j = 0; j < 8; j++) {
    a[j][0] = bf2f(v0[j].x); a[j][1] = bf2f(v0[j].y);
    a[j][2] = bf2f(v0[j].z); a[j][3] = bf2f(v0[j].w);
  }

#pragma unroll
  for (int j = 0; j < 8; j++) {
    for (int p = lo[j] + 1; p < hi[j]; ++p) {
      int r = rows[p];
      ushort4 v = *(const ushort4*)(h + (size_t)r * D + lane * 4);
      a[j][0] += bf2f(v.x); a[j][1] += bf2f(v.y);
      a[j][2] += bf2f(v.z); a[j][3] += bf2f(v.w);
    }
  }

#pragma unroll
  for (int j = 0; j < 8; j++) {
    int id = base + j;
    if (id >= RN) continue;
    int c = hi[j] - lo[j];
    float inv = 1.0f / (float)(c > 0 ? c : 1);
    ushort4 o;
    o.x = f2bf(a[j][0] * inv); o.y = f2bf(a[j][1] * inv);
    o.z = f2bf(a[j][2] * inv); o.w = f2bf(a[j][3] * inv);
    *(ushort4*)(out + (size_t)id * D + lane * 4) = o;
  }
}

// ---------------- fused K=1024 bf16 MFMA GEMM, 128x256 block, 8 waves ------
// ROUND-8 PROVEN SHAPE (96.6 us): BK=32, 30 KB LDS, VGPR 56. Do NOT raise BK
// (round 9: BK=64 -> spill, 2.5x slower). Do NOT use cooperative grid.sync
// (round 12: ~100 us per sync). SQ_LDS_BANK_CONFLICT ~1.1e7 is intrinsic
// b128 multi-phase service, not fixable aliasing.
__global__ __launch_bounds__(512) void k_lgemm(
    const unsigned short* __restrict__ Aroot, const int* __restrict__ gidx,
    const unsigned short* agg, const unsigned short* __restrict__ wb,
    const float* __restrict__ bias, unsigned short* Cout, int M, int N) {
  __shared__ unsigned short AsU[128 * 40];       // 10 KB [row][k] pad->40
  __shared__ unsigned short BsU[256 * 40];       // 20 KB [n][k]   pad->40
  const int tid = threadIdx.x;
  const int w = tid >> 6, lane = tid & 63;
  const int wr = w >> 2, wc = w & 3;             // wave grid 2x4
  const int i0 = blockIdx.x * 128;
  const int ml = lane & 15, q = lane >> 4;

  const int srow = tid >> 2;       // 0..127
  const int schunk = tid & 3;      // 16B chunk within 64B k-slice
  int r0 = i0 + srow;
  int r0c = (r0 < M) ? r0 : (M - 1);
  const int rowA0 = gidx ? gidx[r0c] : r0c;

  const unsigned short* a0base[4];
  a0base[0] = Aroot + (size_t)rowA0 * D + schunk * 8;
#pragma unroll
  for (int r = 0; r < 3; r++)
    a0base[r + 1] = agg + ((size_t)r * N + r0c) * D + schunk * 8;

  floatx4 acc[4][4];
#pragma unroll
  for (int i = 0; i < 4; i++)
#pragma unroll
    for (int j = 0; j < 4; j++) acc[i][j] = (floatx4){0.f, 0.f, 0.f, 0.f};

  // prefetch registers (step 0)
  uint4 av0, bv0, bv1;
  {
    av0 = *(const uint4*)(a0base[0]);
    const unsigned short* bb = wb + (size_t)srow * D + schunk * 8;
    bv0 = *(const uint4*)(bb);
    bv1 = *(const uint4*)(bb + 128 * D);
  }

  for (int step = 0; step < 32; ++step) {
    __syncthreads();   // previous step's LDS consumers done
    *(uint4*)&AsU[srow * 40 + schunk * 8] = av0;
    *(uint4*)&BsU[srow * 40 + schunk * 8] = bv0;
    *(uint4*)&BsU[(srow + 128) * 40 + schunk * 8] = bv1;
    __syncthreads();

    // issue next step's loads now — they fly under the compute below
    {
      int ns = (step < 31) ? step + 1 : 31;
      int seg = ns >> 3, kloc = (ns & 7) * 32;
      av0 = *(const uint4*)(a0base[seg] + kloc);
      const unsigned short* bb =
          wb + (size_t)seg * 65536 + (size_t)srow * D + schunk * 8 + kloc;
      bv0 = *(const uint4*)(bb);
      bv1 = *(const uint4*)(bb + 128 * D);
    }

    short8 aF[4], bF[4];
#pragma unroll
    for (int mi = 0; mi < 4; mi++)
      aF[mi] = *(const short8*)&AsU[(wr * 64 + mi * 16 + ml) * 40 + q * 8];
#pragma unroll
    for (int ni = 0; ni < 4; ni++)
      bF[ni] = *(const short8*)&BsU[(wc * 64 + ni * 16 + ml) * 40 + q * 8];
#pragma unroll
    for (int mi = 0; mi < 4; mi++)
#pragma unroll
      for (int ni = 0; ni < 4; ni++)
        acc[mi][ni] = __builtin_amdgcn_mfma_f32_16x16x32_bf16(
            aF[mi], bF[ni], acc[mi][ni], 0, 0, 0);
  }

  // epilogue: bias + ReLU + bf16; C/D layout col=lane&15, row=q*4+reg
  float bv[4];
#pragma unroll
  for (int ni = 0; ni < 4; ni++) bv[ni] = bias[wc * 64 + ni * 16 + ml];
#pragma unroll
  for (int mi = 0; mi < 4; mi++) {
#pragma unroll
    for (int ni = 0; ni < 4; ni++) {
      int col = wc * 64 + ni * 16 + ml;
#pragma unroll
      for (int j = 0; j < 4; j++) {
        int row = i0 + wr * 64 + mi * 16 + q * 4 + j;
        if (row < M) {
          float v = fmaxf(acc[mi][ni][j] + bv[ni], 0.f);
          Cout[(size_t)row * D + col] = f2bf(v);
        }
      }
    }
  }
}

// ---------------- fused graph mean-pool + linear head ----------------
__global__ __launch_bounds__(256) void k_poolfinal(
    const unsigned short* __restrict__ h, const int* __restrict__ gstart,
    const float* __restrict__ linW, const float* __restrict__ linb,
    float* __restrict__ out, int G) {
  __shared__ float red[4][D];
  __shared__ float sred[4][4];
  int g = blockIdx.x;
  int lo = gstart[g], hi = gstart[g + 1];
  int tid = threadIdx.x, wave = tid >> 6, lane = tid & 63;
  float a0 = 0.f, a1 = 0.f, a2 = 0.f, a3 = 0.f;
  for (int i = lo + wave; i < hi; i += 4) {
    ushort4 v = *(const ushort4*)(h + (size_t)i * D + lane * 4);
    a0 += bf2f(v.x); a1 += bf2f(v.y); a2 += bf2f(v.z); a3 += bf2f(v.w);
  }
  red[wave][lane * 4 + 0] = a0;
  red[wave][lane * 4 + 1] = a1;
  red[wave][lane * 4 + 2] = a2;
  red[wave][lane * 4 + 3] = a3;
  __syncthreads();
  float s = red[0][tid] + red[1][tid] + red[2][tid] + red[3][tid];
  float inv = (hi > lo) ? 1.0f / (float)(hi - lo) : 0.0f;
  float m = s * inv;                       // mean feature tid
  float4 wrow = *(const float4*)(linW + tid * 4);
  float p0 = m * wrow.x, p1 = m * wrow.y, p2 = m * wrow.z, p3 = m * wrow.w;
  for (int o = 32; o > 0; o >>= 1) {
    p0 += __shfl_down(p0, o, 64);
    p1 += __shfl_down(p1, o, 64);
    p2 += __shfl_down(p2, o, 64);
    p3 += __shfl_down(p3, o, 64);
  }
  if (lane == 0) {
    sred[wave][0] = p0; sred[wave][1] = p1;
    sred[wave][2] = p2; sred[wave][3] = p3;
  }
  __syncthreads();
  if (tid < 4)
    out[g * 4 + tid] = sred[0][tid] + sred[1][tid] + sred[2][tid] +
                       sred[3][tid] + linb[tid];
}

extern "C" void kernel_launch(void* const* d_in, const int* in_sizes, int n_in,
                              void* d_out, int out_size, void* d_ws, size_t ws_size,
                              hipStream_t stream) {
  const int*   x     = (const int*)d_in[0];
  const int*   ei    = (const int*)d_in[1];
  const int*   et    = (const int*)d_in[2];
  const int*   batch = (const int*)d_in[3];
  const float* table = (const float*)d_in[5];
  const float* W1    = (const float*)d_in[6];
  const float* root1 = (const float*)d_in[7];
  const float* b1    = (const float*)d_in[8];
  const float* W2    = (const float*)d_in[9];
  const float* root2 = (const float*)d_in[10];
  const float* b2    = (const float*)d_in[11];
  const float* linW  = (const float*)d_in[12];
  const float* linb  = (const float*)d_in[13];
  float* out = (float*)d_out;

  const int N = in_sizes[0];
  const int E = in_sizes[2];
  const int G = out_size / 4;
  const int VOC = in_sizes[5] / D;
  const int* src = ei;
  const int* dst = ei + E;
  const int RN = 3 * N;

  // ---- ws layout (~210 MB), page aliasing proven rounds 5-11 ----
  char* wsb = (char*)d_ws;
  size_t pg = (size_t)N * D * 2;
  unsigned short* P0 = (unsigned short*)wsb;
  unsigned short* P1 = (unsigned short*)(wsb + pg);
  unsigned short* P3 = (unsigned short*)(wsb + 3 * pg);
  unsigned short* wb = (unsigned short*)(wsb + 4 * pg);  // 2 layers x 4 mats
  int*   off    = (int*)(wb + 2 * 4 * 65536);
  int*   esx    = off + (RN + 1);       // L1 row ids (= x[src])
  int*   ess    = esx + E;              // L2 row ids (= src)
  int*   gstart = ess + E;
  int*   flags  = gstart + (G + 1);     // nb ints, lookback flags
  int*   aggv   = flags + 512;
  int*   incv   = aggv + 512;
  unsigned short* tableb = P3;          // alias (dead before L2 agg writes P3)
  int* cur  = (int*)P0;                 // alias (dead before L1 agg writes P0)

  const int nb = (RN + 1023) / 1024;    // 293 blocks, all co-resident

  // ---- setup: one fused kernel for all independent prep ----
  int nbZero = (RN + 1023) / 1024;
  int nbBounds = (N + 255) / 256;
  int nbCvt = (VOC * D + 255) / 256;
  int g0 = nbZero, g1 = g0 + nbBounds, g2 = g1 + nbCvt, g3 = g2 + 1024;
  k_setup<<<g3 + 1024, 256, 0, stream>>>(cur, RN, flags, nb, batch, gstart,
      N, G, table, tableb, VOC * D, root1, W1, root2, W2, wb, g0, g1, g2, g3);

  k_count_i<<<(E + 255) / 256, 256, 0, stream>>>(dst, et, cur, E, N);
  k_scanlb<<<nb, 256, 0, stream>>>(cur, off, cur, flags, aggv, incv, RN, nb);
  k_place2<<<(E + 255) / 256, 256, 0, stream>>>(src, dst, et, x, cur, esx, ess, E, N);

  const int gagg = (RN + 31) / 32;      // 8 ids/wave x 4 waves
  const int ggemm = (N + 127) / 128;

  // ---- layer 1 ----
  k_agg<<<gagg, 256, 0, stream>>>(tableb, esx, off, P0, RN);
  k_lgemm<<<ggemm, 512, 0, stream>>>(tableb, x, P0, wb, b1, P0, N, N);
  // ---- layer 2 ----
  k_agg<<<gagg, 256, 0, stream>>>(P0, ess, off, P1, RN);
  k_lgemm<<<ggemm, 512, 0, stream>>>(P0, nullptr, P1, wb + 4 * 65536, b2, P1, N, N);

  // ---- pool + head fused ----
  k_poolfinal<<<G, 256, 0, stream>>>(P1, gstart, linW, linb, out, G);
}

// Round 14
// 431.321 us; speedup vs baseline: 2.1222x; 1.0533x over previous
//
#include <hip/hip_runtime.h>

#define D 256
#define SB 1024
typedef __attribute__((ext_vector_type(8))) short short8;
typedef __attribute__((ext_vector_type(4))) float floatx4;

__device__ __forceinline__ unsigned short f2bf(float f) {
  unsigned int u = __float_as_uint(f);
  u = (u + 0x7FFF + ((u >> 16) & 1)) >> 16;   // RNE
  return (unsigned short)u;
}
__device__ __forceinline__ float bf2f(unsigned short h) {
  return __uint_as_float(((unsigned int)h) << 16);
}

// ---------------- fused independent setup: zero | bounds | cvt | cvt_w x2 --
__global__ __launch_bounds__(256) void k_setup(
    int* __restrict__ cur, int RN,
    const int* __restrict__ batch, int* __restrict__ gstart, int N, int G,
    const float* __restrict__ table, unsigned short* __restrict__ tableb, int TN,
    const float* __restrict__ root1, const float* __restrict__ W1,
    const float* __restrict__ root2, const float* __restrict__ W2,
    unsigned short* __restrict__ wb,
    int g0, int g1, int g2, int g3) {
  int b = blockIdx.x, t = threadIdx.x;
  if (b < g0) {                       // zero cur, int4 per thread
    int i = b * 1024 + t * 4;
#pragma unroll
    for (int j = 0; j < 4; j++) if (i + j < RN) cur[i + j] = 0;
  } else if (b < g1) {                // graph bounds
    int i = (b - g0) * 256 + t;
    if (i >= N) return;
    int bb = batch[i];
    if (i == 0) { for (int g = 0; g <= bb; g++) gstart[g] = 0; }
    else { int pb = batch[i - 1]; for (int g = pb + 1; g <= bb; g++) gstart[g] = i; }
    if (i == N - 1) { for (int g = bb + 1; g <= G; g++) gstart[g] = N; }
  } else if (b < g2) {                // table fp32 -> bf16
    int i = (b - g1) * 256 + t;
    if (i < TN) tableb[i] = f2bf(table[i]);
  } else {                            // weights -> bf16 transposed [mat][n][k]
    int layer = (b < g3) ? 0 : 1;
    int idx = ((b - (layer ? g3 : g2)) * 256 + t);   // 0 .. 4*65536-1
    int mat = idx >> 16, rem = idx & 65535;
    int n = rem >> 8, k = rem & 255;
    const float* root = layer ? root2 : root1;
    const float* W = layer ? W2 : W1;
    const float* s = (mat == 0) ? root : (W + (size_t)(mat - 1) * 65536);
    wb[(size_t)layer * 4 * 65536 + idx] = f2bf(s[k * 256 + n]);
  }
}

// ---------------- per-(relation,node) in-edge counts ----------------
__global__ __launch_bounds__(256) void k_count_i(const int* __restrict__ dst,
    const int* __restrict__ et, int* __restrict__ cnt, int E, int N) {
  int e = blockIdx.x * 256 + threadIdx.x;
  if (e >= E) return;
  atomicAdd(&cnt[et[e] * N + dst[e]], 1);
}

// ---------------- 3-kernel scan chain (proven round 11; the single-pass
// lookback variant regressed ~21 us and relied on volatile flag spins that
// are unsafe across non-coherent XCD L2s — do not reintroduce) ----------
__global__ __launch_bounds__(256) void k_scan1(const int* __restrict__ in,
    int* __restrict__ bsum, int n) {
  __shared__ int s[256];
  int base = blockIdx.x * SB, t = threadIdx.x;
  int a = 0;
#pragma unroll
  for (int j = 0; j < 4; j++) { int i = base + t * 4 + j; if (i < n) a += in[i]; }
  s[t] = a; __syncthreads();
  for (int o = 128; o > 0; o >>= 1) { if (t < o) s[t] += s[t + o]; __syncthreads(); }
  if (t == 0) bsum[blockIdx.x] = s[0];
}

__global__ __launch_bounds__(256) void k_scan2(int* __restrict__ bsum, int nb,
    int* __restrict__ total_out) {
  __shared__ int s[256];
  int t = threadIdx.x;
  int v[4]; int a = 0;
#pragma unroll
  for (int j = 0; j < 4; j++) {
    int i = t * 4 + j;
    v[j] = (i < nb) ? bsum[i] : 0;
    a += v[j];
  }
  s[t] = a; __syncthreads();
  for (int o = 1; o < 256; o <<= 1) {
    int x_ = (t >= o) ? s[t - o] : 0;
    __syncthreads();
    s[t] += x_;
    __syncthreads();
  }
  int excl = (t > 0) ? s[t - 1] : 0;
#pragma unroll
  for (int j = 0; j < 4; j++) {
    int i = t * 4 + j;
    if (i < nb) { bsum[i] = excl; excl += v[j]; }
  }
  if (t == 255) *total_out = s[255];
}

__global__ __launch_bounds__(256) void k_scan3(const int* __restrict__ in,
    const int* __restrict__ bsum, int* __restrict__ off, int* __restrict__ cur,
    int n) {
  __shared__ int s[256];
  int base = blockIdx.x * SB, t = threadIdx.x;
  int v[4]; int a = 0;
#pragma unroll
  for (int j = 0; j < 4; j++) {
    int i = base + t * 4 + j;
    v[j] = (i < n) ? in[i] : 0;
    a += v[j];
  }
  s[t] = a; __syncthreads();
  for (int o = 1; o < 256; o <<= 1) {
    int x_ = (t >= o) ? s[t - o] : 0;
    __syncthreads();
    s[t] += x_;
    __syncthreads();
  }
  int excl = (t > 0 ? s[t - 1] : 0) + bsum[blockIdx.x];
#pragma unroll
  for (int j = 0; j < 4; j++) {
    int i = base + t * 4 + j;
    if (i < n) { off[i] = excl; cur[i] = excl; excl += v[j]; }
  }
}

// CSR placement: esx[pos] = x[src] (L1 row id), ess[pos] = src (L2 row id)
__global__ __launch_bounds__(256) void k_place2(const int* __restrict__ src,
    const int* __restrict__ dst, const int* __restrict__ et,
    const int* __restrict__ x, int* __restrict__ cur,
    int* __restrict__ esx, int* __restrict__ ess, int E, int N) {
  int e = blockIdx.x * 256 + threadIdx.x;
  if (e >= E) return;
  int s = src[e];
  int pos = atomicAdd(&cur[et[e] * N + dst[e]], 1);
  esx[pos] = x[s];
  ess[pos] = s;
}

// ---------------- relation aggregation, 8 ids per wave (ILP batch) --------
__global__ __launch_bounds__(256) void k_agg(const unsigned short* __restrict__ h,
    const int* __restrict__ rows, const int* __restrict__ off,
    unsigned short* __restrict__ out, int RN) {
  const int wave = threadIdx.x >> 6, lane = threadIdx.x & 63;
  const int base = (blockIdx.x * 4 + wave) * 8;
  if (base >= RN) return;

  int lo[8], hi[8];
#pragma unroll
  for (int j = 0; j < 8; j++) {
    int id = base + j;
    lo[j] = (id < RN) ? off[id] : 0;
    hi[j] = (id < RN) ? off[id + 1] : 0;
  }

  int r0[8];
#pragma unroll
  for (int j = 0; j < 8; j++)
    r0[j] = (hi[j] > lo[j]) ? rows[lo[j]] : 0;

  ushort4 v0[8];
#pragma unroll
  for (int j = 0; j < 8; j++)
    v0[j] = (hi[j] > lo[j])
        ? *(const ushort4*)(h + (size_t)r0[j] * D + lane * 4)
        : make_ushort4(0, 0, 0, 0);

  float a[8][4];
#pragma unroll
  for (int j = 0; j < 8; j++) {
    a[j][0] = bf2f(v0[j].x); a[j][1] = bf2f(v0[j].y);
    a[j][2] = bf2f(v0[j].z); a[j][3] = bf2f(v0[j].w);
  }

#pragma unroll
  for (int j = 0; j < 8; j++) {
    for (int p = lo[j] + 1; p < hi[j]; ++p) {
      int r = rows[p];
      ushort4 v = *(const ushort4*)(h + (size_t)r * D + lane * 4);
      a[j][0] += bf2f(v.x); a[j][1] += bf2f(v.y);
      a[j][2] += bf2f(v.z); a[j][3] += bf2f(v.w);
    }
  }

#pragma unroll
  for (int j = 0; j < 8; j++) {
    int id = base + j;
    if (id >= RN) continue;
    int c = hi[j] - lo[j];
    float inv = 1.0f / (float)(c > 0 ? c : 1);
    ushort4 o;
    o.x = f2bf(a[j][0] * inv); o.y = f2bf(a[j][1] * inv);
    o.z = f2bf(a[j][2] * inv); o.w = f2bf(a[j][3] * inv);
    *(ushort4*)(out + (size_t)id * D + lane * 4) = o;
  }
}

// ---------------- fused K=1024 bf16 MFMA GEMM, 128x256 block, 8 waves ------
// ROUND-8/11 PROVEN SHAPE (96.6 us): BK=32, 30 KB LDS, VGPR 56.
// Do NOT: raise BK (r9: spill, 2.5x slower), widen wave tiles (r7: occupancy
// crash), cooperative grid.sync (r12: ~100 us/sync). SQ_LDS_BANK_CONFLICT
// ~1.1e7 is intrinsic b128 multi-phase service, not fixable aliasing.
__global__ __launch_bounds__(512) void k_lgemm(
    const unsigned short* __restrict__ Aroot, const int* __restrict__ gidx,
    const unsigned short* agg, const unsigned short* __restrict__ wb,
    const float* __restrict__ bias, unsigned short* Cout, int M, int N) {
  __shared__ unsigned short AsU[128 * 40];       // 10 KB [row][k] pad->40
  __shared__ unsigned short BsU[256 * 40];       // 20 KB [n][k]   pad->40
  const int tid = threadIdx.x;
  const int w = tid >> 6, lane = tid & 63;
  const int wr = w >> 2, wc = w & 3;             // wave grid 2x4
  const int i0 = blockIdx.x * 128;
  const int ml = lane & 15, q = lane >> 4;

  const int srow = tid >> 2;       // 0..127
  const int schunk = tid & 3;      // 16B chunk within 64B k-slice
  int r0 = i0 + srow;
  int r0c = (r0 < M) ? r0 : (M - 1);
  const int rowA0 = gidx ? gidx[r0c] : r0c;

  const unsigned short* a0base[4];
  a0base[0] = Aroot + (size_t)rowA0 * D + schunk * 8;
#pragma unroll
  for (int r = 0; r < 3; r++)
    a0base[r + 1] = agg + ((size_t)r * N + r0c) * D + schunk * 8;

  floatx4 acc[4][4];
#pragma unroll
  for (int i = 0; i < 4; i++)
#pragma unroll
    for (int j = 0; j < 4; j++) acc[i][j] = (floatx4){0.f, 0.f, 0.f, 0.f};

  // prefetch registers (step 0)
  uint4 av0, bv0, bv1;
  {
    av0 = *(const uint4*)(a0base[0]);
    const unsigned short* bb = wb + (size_t)srow * D + schunk * 8;
    bv0 = *(const uint4*)(bb);
    bv1 = *(const uint4*)(bb + 128 * D);
  }

  for (int step = 0; step < 32; ++step) {
    __syncthreads();   // previous step's LDS consumers done
    *(uint4*)&AsU[srow * 40 + schunk * 8] = av0;
    *(uint4*)&BsU[srow * 40 + schunk * 8] = bv0;
    *(uint4*)&BsU[(srow + 128) * 40 + schunk * 8] = bv1;
    __syncthreads();

    // issue next step's loads now — they fly under the compute below
    {
      int ns = (step < 31) ? step + 1 : 31;
      int seg = ns >> 3, kloc = (ns & 7) * 32;
      av0 = *(const uint4*)(a0base[seg] + kloc);
      const unsigned short* bb =
          wb + (size_t)seg * 65536 + (size_t)srow * D + schunk * 8 + kloc;
      bv0 = *(const uint4*)(bb);
      bv1 = *(const uint4*)(bb + 128 * D);
    }

    short8 aF[4], bF[4];
#pragma unroll
    for (int mi = 0; mi < 4; mi++)
      aF[mi] = *(const short8*)&AsU[(wr * 64 + mi * 16 + ml) * 40 + q * 8];
#pragma unroll
    for (int ni = 0; ni < 4; ni++)
      bF[ni] = *(const short8*)&BsU[(wc * 64 + ni * 16 + ml) * 40 + q * 8];
#pragma unroll
    for (int mi = 0; mi < 4; mi++)
#pragma unroll
      for (int ni = 0; ni < 4; ni++)
        acc[mi][ni] = __builtin_amdgcn_mfma_f32_16x16x32_bf16(
            aF[mi], bF[ni], acc[mi][ni], 0, 0, 0);
  }

  // epilogue: bias + ReLU + bf16; C/D layout col=lane&15, row=q*4+reg
  float bv[4];
#pragma unroll
  for (int ni = 0; ni < 4; ni++) bv[ni] = bias[wc * 64 + ni * 16 + ml];
#pragma unroll
  for (int mi = 0; mi < 4; mi++) {
#pragma unroll
    for (int ni = 0; ni < 4; ni++) {
      int col = wc * 64 + ni * 16 + ml;
#pragma unroll
      for (int j = 0; j < 4; j++) {
        int row = i0 + wr * 64 + mi * 16 + q * 4 + j;
        if (row < M) {
          float v = fmaxf(acc[mi][ni][j] + bv[ni], 0.f);
          Cout[(size_t)row * D + col] = f2bf(v);
        }
      }
    }
  }
}

// ---------------- fused graph mean-pool + linear head ----------------
__global__ __launch_bounds__(256) void k_poolfinal(
    const unsigned short* __restrict__ h, const int* __restrict__ gstart,
    const float* __restrict__ linW, const float* __restrict__ linb,
    float* __restrict__ out, int G) {
  __shared__ float red[4][D];
  __shared__ float sred[4][4];
  int g = blockIdx.x;
  int lo = gstart[g], hi = gstart[g + 1];
  int tid = threadIdx.x, wave = tid >> 6, lane = tid & 63;
  float a0 = 0.f, a1 = 0.f, a2 = 0.f, a3 = 0.f;
  for (int i = lo + wave; i < hi; i += 4) {
    ushort4 v = *(const ushort4*)(h + (size_t)i * D + lane * 4);
    a0 += bf2f(v.x); a1 += bf2f(v.y); a2 += bf2f(v.z); a3 += bf2f(v.w);
  }
  red[wave][lane * 4 + 0] = a0;
  red[wave][lane * 4 + 1] = a1;
  red[wave][lane * 4 + 2] = a2;
  red[wave][lane * 4 + 3] = a3;
  __syncthreads();
  float s = red[0][tid] + red[1][tid] + red[2][tid] + red[3][tid];
  float inv = (hi > lo) ? 1.0f / (float)(hi - lo) : 0.0f;
  float m = s * inv;                       // mean feature tid
  float4 wrow = *(const float4*)(linW + tid * 4);
  float p0 = m * wrow.x, p1 = m * wrow.y, p2 = m * wrow.z, p3 = m * wrow.w;
  for (int o = 32; o > 0; o >>= 1) {
    p0 += __shfl_down(p0, o, 64);
    p1 += __shfl_down(p1, o, 64);
    p2 += __shfl_down(p2, o, 64);
    p3 += __shfl_down(p3, o, 64);
  }
  if (lane == 0) {
    sred[wave][0] = p0; sred[wave][1] = p1;
    sred[wave][2] = p2; sred[wave][3] = p3;
  }
  __syncthreads();
  if (tid < 4)
    out[g * 4 + tid] = sred[0][tid] + sred[1][tid] + sred[2][tid] +
                       sred[3][tid] + linb[tid];
}

extern "C" void kernel_launch(void* const* d_in, const int* in_sizes, int n_in,
                              void* d_out, int out_size, void* d_ws, size_t ws_size,
                              hipStream_t stream) {
  const int*   x     = (const int*)d_in[0];
  const int*   ei    = (const int*)d_in[1];
  const int*   et    = (const int*)d_in[2];
  const int*   batch = (const int*)d_in[3];
  const float* table = (const float*)d_in[5];
  const float* W1    = (const float*)d_in[6];
  const float* root1 = (const float*)d_in[7];
  const float* b1    = (const float*)d_in[8];
  const float* W2    = (const float*)d_in[9];
  const float* root2 = (const float*)d_in[10];
  const float* b2    = (const float*)d_in[11];
  const float* linW  = (const float*)d_in[12];
  const float* linb  = (const float*)d_in[13];
  float* out = (float*)d_out;

  const int N = in_sizes[0];
  const int E = in_sizes[2];
  const int G = out_size / 4;
  const int VOC = in_sizes[5] / D;
  const int* src = ei;
  const int* dst = ei + E;
  const int RN = 3 * N;

  // ---- ws layout (~210 MB), page aliasing proven rounds 5-13 ----
  char* wsb = (char*)d_ws;
  size_t pg = (size_t)N * D * 2;
  unsigned short* P0 = (unsigned short*)wsb;
  unsigned short* P1 = (unsigned short*)(wsb + pg);
  unsigned short* P3 = (unsigned short*)(wsb + 3 * pg);
  unsigned short* wb = (unsigned short*)(wsb + 4 * pg);  // 2 layers x 4 mats
  int*   off    = (int*)(wb + 2 * 4 * 65536);
  int*   esx    = off + (RN + 1);       // L1 row ids (= x[src])
  int*   ess    = esx + E;              // L2 row ids (= src)
  int*   gstart = ess + E;
  unsigned short* tableb = P3;          // alias (dead before L2 agg writes P3)
  int* cur  = (int*)P0;                 // alias (dead before L1 agg writes P0)
  int* bsum = cur + RN;                 // alias

  const int nb = (RN + SB - 1) / SB;

  // ---- setup: one fused kernel for all independent prep ----
  int nbZero = (RN + 1023) / 1024;
  int nbBounds = (N + 255) / 256;
  int nbCvt = (VOC * D + 255) / 256;
  int g0 = nbZero, g1 = g0 + nbBounds, g2 = g1 + nbCvt, g3 = g2 + 1024;
  k_setup<<<g3 + 1024, 256, 0, stream>>>(cur, RN, batch, gstart, N, G,
      table, tableb, VOC * D, root1, W1, root2, W2, wb, g0, g1, g2, g3);

  k_count_i<<<(E + 255) / 256, 256, 0, stream>>>(dst, et, cur, E, N);
  k_scan1<<<nb, 256, 0, stream>>>(cur, bsum, RN);
  k_scan2<<<1, 256, 0, stream>>>(bsum, nb, off + RN);
  k_scan3<<<nb, 256, 0, stream>>>(cur, bsum, off, cur, RN);
  k_place2<<<(E + 255) / 256, 256, 0, stream>>>(src, dst, et, x, cur, esx, ess, E, N);

  const int gagg = (RN + 31) / 32;      // 8 ids/wave x 4 waves
  const int ggemm = (N + 127) / 128;

  // ---- layer 1 ----
  k_agg<<<gagg, 256, 0, stream>>>(tableb, esx, off, P0, RN);
  k_lgemm<<<ggemm, 512, 0, stream>>>(tableb, x, P0, wb, b1, P0, N, N);
  // ---- layer 2 ----
  k_agg<<<gagg, 256, 0, stream>>>(P0, ess, off, P1, RN);
  k_lgemm<<<ggemm, 512, 0, stream>>>(P0, nullptr, P1, wb + 4 * 65536, b2, P1, N, N);

  // ---- pool + head fused ----
  k_poolfinal<<<G, 256, 0, stream>>>(P1, gstart, linW, linb, out, G);
}